// Round 3
// baseline (125.743 us; speedup 1.0000x reference)
//
#include <hip/hip_runtime.h>

#define TT 14
#define LL 26
#define EE 128
#define NB 16384
#define BPB 8              // batches per block
#define ROWS (BPB * TT)    // 112 (b,t) rows per block
#define EPAD 27            // odd pad -> bank-bijective emis writes

// ---------------------------------------------------------------------------
// Setup: fold conv into an effective emission matrix.
//   Weff[e][l] = sum_{ky,kx} conv_w[ky][kx] * Wmat[l][oy*8+ox]
//   be[l]      = conv_b * sum_e Wmat[l][e]
// ---------------------------------------------------------------------------
__global__ __launch_bounds__(256) void crf_setup(
    const float* __restrict__ conv_w, const float* __restrict__ conv_b,
    const float* __restrict__ params, float* __restrict__ weff,
    float* __restrict__ be) {
  int idx = blockIdx.x * 256 + threadIdx.x;
  if (idx < EE * LL) {
    int e = idx / LL, l = idx - e * LL;
    int iy = e >> 3, ix = e & 7;
    float s = 0.f;
    for (int ky = 0; ky < 5; ++ky) {
      int oy = iy - ky + 2;
      if (oy < 0 || oy >= 16) continue;
      for (int kx = 0; kx < 5; ++kx) {
        int ox = ix - kx + 2;
        if (ox < 0 || ox >= 8) continue;
        s += conv_w[ky * 5 + kx] * params[l * EE + oy * 8 + ox];
      }
    }
    weff[e * LL + l] = s;  // [e][l]: main-kernel reads are wave-uniform
  }
  if (idx < LL) {
    float s = 0.f;
    for (int e = 0; e < EE; ++e) s += params[idx * EE + e];
    be[idx] = conv_b[0] * s;
  }
}

// ---------------------------------------------------------------------------
// Fused emission GEMM + Viterbi + backtrack. One block = 8 batches.
// ---------------------------------------------------------------------------
__global__ __launch_bounds__(128, 4) void crf_main(
    const float* __restrict__ X, const float* __restrict__ params,
    const float* __restrict__ weff, const float* __restrict__ be,
    float* __restrict__ out) {
  __shared__ float emis_s[ROWS * EPAD];          // 12096 B
  __shared__ unsigned char bp_s[BPB][TT - 1][28];  // 2912 B

  const int tid = threadIdx.x;
  const int b0 = blockIdx.x * BPB;

  // ---- Phase 1: emissions. Thread tid owns row (b0*14 + tid), tid < 112.
  //      4 independent float4 loads batched per iteration for MLP.
  if (tid < ROWS) {
    const float4* xv =
        reinterpret_cast<const float4*>(X) + (size_t)(b0 * TT + tid) * 32;
    float acc[LL];
#pragma unroll
    for (int l = 0; l < LL; ++l) acc[l] = 0.f;
    for (int c = 0; c < 8; ++c) {
      float4 v0 = xv[c * 4 + 0];
      float4 v1 = xv[c * 4 + 1];
      float4 v2 = xv[c * 4 + 2];
      float4 v3 = xv[c * 4 + 3];
      const float* w = weff + c * 16 * LL;  // wave-uniform -> s_load
#pragma unroll
      for (int l = 0; l < LL; ++l)
        acc[l] += v0.x * w[l] + v0.y * w[LL + l] + v0.z * w[2 * LL + l] +
                  v0.w * w[3 * LL + l];
#pragma unroll
      for (int l = 0; l < LL; ++l)
        acc[l] += v1.x * w[4 * LL + l] + v1.y * w[5 * LL + l] +
                  v1.z * w[6 * LL + l] + v1.w * w[7 * LL + l];
#pragma unroll
      for (int l = 0; l < LL; ++l)
        acc[l] += v2.x * w[8 * LL + l] + v2.y * w[9 * LL + l] +
                  v2.z * w[10 * LL + l] + v2.w * w[11 * LL + l];
#pragma unroll
      for (int l = 0; l < LL; ++l)
        acc[l] += v3.x * w[12 * LL + l] + v3.y * w[13 * LL + l] +
                  v3.z * w[14 * LL + l] + v3.w * w[15 * LL + l];
    }
#pragma unroll
    for (int l = 0; l < LL; ++l) emis_s[tid * EPAD + l] = acc[l] + be[l];
  }
  __syncthreads();

  // ---- Phase 2: Viterbi. Each 32-lane group owns one batch, lane j = label.
  const int lane = tid & 63;
  const int wv = tid >> 6;                 // wave 0..1
  const int j = lane & 31;
  const int hb = lane >> 5;
  const int jj = (j < LL) ? j : (LL - 1);

  // Trans column for this lane, from global (L2-resident), once for both p.
  const float* Tr = params + LL * EE;
  float Tcol[LL];
#pragma unroll
  for (int i = 0; i < LL; ++i) Tcol[i] = Tr[i * LL + jj];  // Trans[i][j]

  for (int p = 0; p < 2; ++p) {
    const int bl = p * 4 + wv * 2 + hb;    // 0..7

    float alpha = emis_s[(bl * TT + 0) * EPAD + jj];
    for (int t = 1; t < TT; ++t) {
      float m = -__builtin_inff();
      int bp = 0;
#pragma unroll
      for (int i = 0; i < LL; ++i) {
        float a_i = __shfl(alpha, i, 32);
        float s = a_i + Tcol[i];
        if (s > m) { m = s; bp = i; }      // strict > : first-index tie-break
      }
      alpha = m + emis_s[(bl * TT + t) * EPAD + jj];
      if (j < LL) bp_s[bl][t - 1][j] = (unsigned char)bp;
    }

    // argmax over labels (max value, lowest index on tie)
    float val = (j < LL) ? alpha : -__builtin_inff();
    int idx = j;
#pragma unroll
    for (int off = 16; off >= 1; off >>= 1) {
      float v2 = __shfl_xor(val, off, 32);
      int i2 = __shfl_xor(idx, off, 32);
      if (v2 > val || (v2 == val && i2 < idx)) { val = v2; idx = i2; }
    }

    __syncthreads();  // bp_s writes visible before backtrack

    if (j == 0) {
      const int b = b0 + bl;
      out[(size_t)NB * TT + b] = val;  // score
      int lbl = idx;
      for (int t = TT - 1; t >= 1; --t) {
        out[(size_t)b * TT + t] = (float)lbl;
        lbl = bp_s[bl][t - 1][lbl];
      }
      out[(size_t)b * TT + 0] = (float)lbl;
    }
    __syncthreads();
  }
}

extern "C" void kernel_launch(void* const* d_in, const int* in_sizes, int n_in,
                              void* d_out, int out_size, void* d_ws,
                              size_t ws_size, hipStream_t stream) {
  const float* X = (const float*)d_in[0];
  const float* conv_w = (const float*)d_in[1];
  const float* conv_b = (const float*)d_in[2];
  const float* params = (const float*)d_in[3];
  float* out = (float*)d_out;
  float* weff = (float*)d_ws;  // 3328 floats
  float* be = weff + EE * LL;  // 26 floats

  hipLaunchKernelGGL(crf_setup, dim3(13), dim3(256), 0, stream, conv_w, conv_b,
                     params, weff, be);
  hipLaunchKernelGGL(crf_main, dim3(NB / BPB), dim3(128), 0, stream, X, params,
                     weff, be, out);
}